// Round 12
// baseline (470.608 us; speedup 1.0000x reference)
//
#include <hip/hip_runtime.h>
#include <cfloat>
#include <climits>
#include <math.h>

#define SRATE 22050.0
#define WMAX 512
#define RCAP 128
#define LCR 256
#define RCR 512
#define SCAP 16384
#define OPR 256
#define MSL 3072
#define NTW 256
#define PCAP 8192
#define FCAP 16384
#define PSTG 4096
#define SNDW 15872
#define RPW 136
#define APPLYB 2048
#define TAILB 1024

// scal layout: 0 gp_bits, 1 minpos_bits, 2 median_bits, 3 has_pos, 4 n_peaks,
// 6 tail, 8 ns0, 9 ne0, 10 ns1, 11 ne1, 12 nreg0, 13 nreg1, 14 nreg1_eff,
// 15 n_pos, 16 f0[1] bits, 17 f0s[1] bits

// ---- fused stats: scal init + positive count/flag + radix-select median ----
__global__ __launch_bounds__(256) void kstats(const float* __restrict__ pitch, int S, unsigned* scal) {
  __shared__ float sp[MSL];
  __shared__ int sc[256];
  __shared__ int sa[256];
  __shared__ unsigned hist[256];
  __shared__ unsigned sprefix, smask;
  __shared__ int srank;
  int tid = threadIdx.x;
  if (tid < 64) scal[tid] = (tid == 1) ? 0x7f800000u : 0u;
  bool lds = (S <= MSL);
  int c = 0, a = 0;
  for (int j = tid; j < S; j += 256) {
    float v = pitch[j];
    if (lds) sp[j] = v;
    if (v > 0.0f) c++;
    if (v > 1e-05f) a = 1;
  }
  sc[tid] = c; sa[tid] = a; __syncthreads();
  for (int st = 128; st; st >>= 1) {
    if (tid < st) { sc[tid] += sc[tid + st]; sa[tid] |= sa[tid + st]; }
    __syncthreads();
  }
  int n = sc[0];
  if (tid == 0) { scal[15] = (unsigned)n; scal[3] = (unsigned)sa[0]; }
  if (n == 0) return;
  if (tid == 0) { sprefix = 0u; smask = 0u; srank = (n - 1) >> 1; }
  __syncthreads();
  for (int shift = 24; shift >= 0; shift -= 8) {
    hist[tid] = 0u;
    __syncthreads();
    unsigned pfx = sprefix, msk = smask;
    for (int q = tid; q < S; q += 256) {
      float v = lds ? sp[q] : pitch[q];
      if (v > 0.0f) {
        unsigned u = __float_as_uint(v);
        if ((u & msk) == pfx) atomicAdd(&hist[(u >> shift) & 255u], 1u);
      }
    }
    __syncthreads();
    if (tid == 0) {
      int r = srank;
      unsigned b = 0;
      for (;;) { unsigned cc = hist[b]; if (r < (int)cc) break; r -= (int)cc; b++; }
      srank = r;
      sprefix = pfx | (b << shift);
      smask = msk | (0xFFu << shift);
    }
    __syncthreads();
  }
  if (tid == 0) scal[2] = sprefix;
}

__device__ __forceinline__ float interp1(const float* __restrict__ pitch, int S, double r, int t) {
  double x = ((double)t + 0.5) * r - 0.5;
  if (x < 0.0) x = 0.0;
  double sm1 = (double)(S - 1);
  if (x > sm1) x = sm1;
  double fl = floor(x);
  int i0 = (int)fl;
  int i1 = i0 + 1; if (i1 > S - 1) i1 = S - 1;
  float f = (float)(x - fl);
  return __fadd_rn(__fmul_rn(pitch[i0], __fsub_rn(1.0f, f)), __fmul_rn(pitch[i1], f));
}

// ---- fused: pd/w0 tables, gp, minpos, region transitions, f0[1]/f0s[1] ----
__global__ __launch_bounds__(256) void kprep(const float* __restrict__ pitch, int S, int T,
                                             const float* __restrict__ snd, unsigned* scal,
                                             const int* __restrict__ steps_p, const float* __restrict__ pr_p,
                                             int* __restrict__ pd, int* __restrict__ w0,
                                             int* s0l, int* e0l, int* s1l, int* e1l) {
  __shared__ float smax[256];
  __shared__ unsigned smin[256];
  float med = __uint_as_float(scal[2]);
  double factor = exp2((double)steps_p[0] / 12.0);
  float fac32 = (float)factor;
  float m32 = (float)((double)med * factor);
  float pr32 = pr_p[0];
  double r = (double)S / (double)T;
  float amax = 0.0f;
  unsigned lmin = 0x7f800000u;
  int lane = threadIdx.x & 63;
  int stride = gridDim.x * blockDim.x;
  for (int t = blockIdx.x * blockDim.x + threadIdx.x; t < T; t += stride) {
    float v = interp1(pitch, S, r, t);
    float v1 = __fmul_rn(v, fac32);
    float vs = 0.0f;
    if (v1 > 0.0f) vs = __fadd_rn(m32, __fmul_rn(__fsub_rn(v1, m32), pr32));
    if (t == 1) { scal[16] = __float_as_uint(v); scal[17] = __float_as_uint(vs); }
    { double fd = (double)vs; if (fd < 60.0) fd = 60.0; pd[t] = (int)(SRATE / fd); }
    { double fi = (double)v; if (fi < 60.0) fi = 60.0;
      int ww = (int)(SRATE / fi); if (ww < 1) ww = 1; if (ww > WMAX - 1) ww = WMAX - 1;
      w0[t] = ww; }
    if (vs > 0.0f) { unsigned b = __float_as_uint(vs); if (b < lmin) lmin = b; }
    float a = fabsf(snd[t]); if (a > amax) amax = a;
    bool pv = false, pv1 = false;
    float upv = __shfl_up(v, 1, 64);
    if (t > 0) {
      float pvv = (lane == 0) ? interp1(pitch, S, r, t - 1) : upv;
      pv = pvv > 0.0f;
      float pm1 = __fmul_rn(pvv, fac32);
      float pvs = 0.0f;
      if (pm1 > 0.0f) pvs = __fadd_rn(m32, __fmul_rn(__fsub_rn(pm1, m32), pr32));
      pv1 = pvs > 0.0f;
    }
    bool cv = v > 0.0f, cv1 = vs > 0.0f;
    if (cv && (t == 0 || !pv))  { unsigned k = atomicAdd(scal + 8, 1u);  if (k < RCAP) s0l[k] = t; }
    if (!cv && t > 0 && pv)     { unsigned k = atomicAdd(scal + 9, 1u);  if (k < RCAP) e0l[k] = t; }
    if (cv1 && (t == 0 || !pv1)){ unsigned k = atomicAdd(scal + 10, 1u); if (k < RCAP) s1l[k] = t; }
    if (!cv1 && t > 0 && pv1)   { unsigned k = atomicAdd(scal + 11, 1u); if (k < RCAP) e1l[k] = t; }
  }
  smax[threadIdx.x] = amax; smin[threadIdx.x] = lmin; __syncthreads();
  for (int st = 128; st; st >>= 1) {
    if (threadIdx.x < st) {
      float o = smax[threadIdx.x + st]; if (o > smax[threadIdx.x]) smax[threadIdx.x] = o;
      unsigned u = smin[threadIdx.x + st]; if (u < smin[threadIdx.x]) smin[threadIdx.x] = u;
    }
    __syncthreads();
  }
  if (threadIdx.x == 0) {
    atomicMax(scal + 0, __float_as_uint(smax[0]));
    atomicMin(scal + 1, smin[0]);
  }
}

// parallel rank sort (distinct values) in LDS
__device__ void ranksort(int* a, int n, int tid, int* tmp) {
  int v = 0, rk = 0;
  if (tid < n) {
    v = a[tid];
    for (int q = 0; q < n; q++) if (a[q] < v) rk++;
  }
  __syncthreads();
  if (tid < n) tmp[rk] = v;
  __syncthreads();
  if (tid < n) a[tid] = tmp[tid];
  __syncthreads();
}

// pairing over LDS arrays; reproduces repeated _find_voiced semantics
__device__ int pair_regions_lds(float f1, int T, int* sl, int ns, int* el, int ne, int* L, int* R) {
  int b = 0;
  if (ns > 0 && sl[0] == 0) {
    if (T > 1 && f1 > 0.0f) sl[0] = 1;
    else b = 1;
  }
  int m = 0, j = 0;
  for (int k = b; k < ns; k++) {
    int Lv = sl[k];
    while (j < ne && el[j] <= Lv) j++;
    int Rv = (j < ne) ? el[j] : T;
    if (m < RCAP) { L[m] = Lv; R[m] = Rv; m++; }
  }
  return m;
}

struct FPRes { int w; int i; float corr; float peak; };
struct FPG { int w, s, cl, nw, rlen; bool ok; };

// geometry from a precomputed (already clamped) window length w
__device__ __forceinline__ FPG fp_geom(int T, int i, int w, bool right_dir) {
  FPG g;
  int s = i - w / 2; if (s < 0) s = 0;
  int cl, cr;
  if (right_dir) {
    cl = (int)((double)i + 0.3 * (double)w);
    cr = (int)((double)i + 0.75 * (double)w);
  } else {
    double al = (double)i - 1.75 * (double)w;
    double bl = (double)i - 1.3 * (double)w;
    cl = (int)al; if (cl < 0) cl = 0;
    cr = (int)bl; if (cr < 0) cr = 0;
  }
  g.w = w; g.s = s; g.cl = cl;
  g.ok = !(cl == cr || T - cl < w);
  int nw = (((cr + w) < T ? (cr + w) : T)) - cl - w + 1;
  if (nw < 1) nw = 1;
  g.nw = nw;
  int rlen = T - s; if (rlen > w) rlen = w;
  g.rlen = rlen;
  return g;
}

// r7 fp_impl (proven): 2 barriers, deinterleaved ref (ds_read_b128, RPW=136),
// trimmed argmax.
template <bool L>
__device__ __forceinline__ FPRes fp_impl(const float* __restrict__ snd, const float* lsnd, int wb0,
                                         FPG g, int i, int tid,
                                         float (*refp)[RPW], double* sdd, float* swf, int* swi, float* swp) {
  FPRes res;
  int w = g.w, s = g.s, cl = g.cl, nw = g.nw, rlen = g.rlen;
  res.w = w;
  int lane = tid & 63, wv = tid >> 6;
  // stage ref (deinterleaved) + ref norm^2 (barrier 1 covers refp and sdd)
  double part = 0.0;
  for (int k = tid; k < w; k += NTW) {
    float v = (k < rlen) ? (L ? lsnd[s + k - wb0] : snd[s + k]) : 0.0f;
    refp[k & 3][k >> 2] = v;
    part += (double)v * (double)v;
  }
  for (int off = 32; off; off >>= 1) part += __shfl_xor(part, off, 64);
  if (lane == 0) sdd[wv] = part;
  __syncthreads();  // barrier 1
  double refden = sqrt(sdd[0] + sdd[1] + sdd[2] + sdd[3]);
  if (refden < 1e-12) refden = 1e-12;
  // candidates: group g = tid>>2 (64 groups), sub-lane = tid&3
  int gg = tid >> 2, sub = tid & 3;
  float bestv = -FLT_MAX; int bestr = INT_MAX; float bestp = 0.0f;
  for (int base = 0; base < nw; base += 64) {
    int r = base + gg;
    if (r < nw) {
      const float* seg = (L ? (lsnd + (cl - wb0)) : (snd + cl)) + r;
      const float* rrow = refp[sub];
      double d0 = 0.0, d1 = 0.0, n0 = 0.0, n1 = 0.0;
      float pkc = 0.0f;
      int k = sub, j = 0;
      for (; k + 12 < w; k += 16, j += 4) {
        float4 rv = *reinterpret_cast<const float4*>(rrow + j);
        float a0f = seg[k], a1f = seg[k + 4];
        pkc = fmaxf(pkc, fabsf(a0f));
        pkc = fmaxf(pkc, fabsf(a1f));
        double a0 = (double)a0f, a1 = (double)a1f;
        d0 += a0 * (double)rv.x; n0 += a0 * a0;
        d1 += a1 * (double)rv.y; n1 += a1 * a1;
        float a2f = seg[k + 8], a3f = seg[k + 12];
        pkc = fmaxf(pkc, fabsf(a2f));
        pkc = fmaxf(pkc, fabsf(a3f));
        double a2 = (double)a2f, a3 = (double)a3f;
        d0 += a2 * (double)rv.z; n0 += a2 * a2;
        d1 += a3 * (double)rv.w; n1 += a3 * a3;
      }
      for (; k + 4 < w; k += 8) {
        float a0f = seg[k], a1f = seg[k + 4];
        pkc = fmaxf(pkc, fabsf(a0f));
        pkc = fmaxf(pkc, fabsf(a1f));
        double a0 = (double)a0f, b0 = (double)refp[k & 3][k >> 2];
        double a1 = (double)a1f, b1 = (double)refp[(k + 4) & 3][(k + 4) >> 2];
        d0 += a0 * b0; n0 += a0 * a0;
        d1 += a1 * b1; n1 += a1 * a1;
      }
      for (; k < w; k += 4) {
        float af = seg[k];
        pkc = fmaxf(pkc, fabsf(af));
        double a = (double)af; d0 += a * (double)refp[k & 3][k >> 2]; n0 += a * a;
      }
      double dot = d0 + d1, nr2 = n0 + n1;
      dot += __shfl_xor(dot, 1, 64); nr2 += __shfl_xor(nr2, 1, 64);
      pkc = fmaxf(pkc, __shfl_xor(pkc, 1, 64));
      dot += __shfl_xor(dot, 2, 64); nr2 += __shfl_xor(nr2, 2, 64);
      pkc = fmaxf(pkc, __shfl_xor(pkc, 2, 64));
      if (sub == 0) {
        double den = sqrt(nr2); if (den < 1e-12) den = 1e-12;
        float c = (float)(dot / (den * refden));
        if (c > bestv) { bestv = c; bestr = r; bestp = pkc; }
      }
    }
  }
  // wave argmax over sub==0 lanes: levels 32..4 only (low-2-bit lanes never mix)
  for (int off = 32; off >= 4; off >>= 1) {
    float ov = __shfl_xor(bestv, off, 64);
    int orr = __shfl_xor(bestr, off, 64);
    float op = __shfl_xor(bestp, off, 64);
    if (ov > bestv || (ov == bestv && orr < bestr)) { bestv = ov; bestr = orr; bestp = op; }
  }
  if (lane == 0) { swf[wv] = bestv; swi[wv] = bestr; swp[wv] = bestp; }
  __syncthreads();  // barrier 2
  float bv = swf[0]; int br = swi[0]; float bp = swp[0];
  for (int q = 1; q < 4; q++) {
    float ov = swf[q]; int orr = swi[q]; float op = swp[q];
    if (ov > bv || (ov == bv && orr < br)) { bv = ov; br = orr; bp = op; }
  }
  res.corr = bv;
  res.i = i + (br + cl) - s;
  res.peak = bp;
  return res;
}

__device__ __forceinline__ FPRes find_peak_block(const float* __restrict__ snd,
                                                 const float* lsnd, int wb0, int wb1, bool useW,
                                                 int T, int i, int wcur, bool right_dir, int tid,
                                                 float (*refp)[RPW], double* sdd,
                                                 float* swf, int* swi, float* swp) {
  FPG g = fp_geom(T, i, wcur, right_dir);
  if (!g.ok) { FPRes r; r.w = g.w; r.corr = -1.0f; r.i = i; r.peak = 0.0f; return r; }
  int lo_a = g.s < g.cl ? g.s : g.cl;
  int hi1 = g.s + g.w, hi2 = g.cl + g.nw + g.w;
  int hi_a = hi1 > hi2 ? hi1 : hi2;
  bool inW = useW && lo_a >= wb0 && hi_a <= wb1;
  if (inW) return fp_impl<true>(snd, lsnd, wb0, g, i, tid, refp, sdd, swf, swi, swp);
  return fp_impl<false>(snd, lsnd, wb0, g, i, tid, refp, sdd, swf, swi, swp);
}

// ---- walks: one block (256 threads) per (region, direction); regions
// computed IN-BLOCK (replicated kregsort2 pairing — identical int math on
// identical inputs -> identical regions; eliminates the kregsort2 launch). ----
__global__ __launch_bounds__(NTW) void kwalk(const float* __restrict__ snd,
                                             const float* __restrict__ pitch, int S,
                                             const int* __restrict__ w0,
                                             int T, const unsigned* scal,
                                             const int* __restrict__ s0l, const int* __restrict__ e0l,
                                             int2* __restrict__ lcand, int* __restrict__ lcnt,
                                             int* __restrict__ rpk, int* __restrict__ rcnt) {
  __shared__ float lsnd[SNDW];
  __shared__ short swtab[SNDW];
  __shared__ __align__(16) float refp[4][RPW];
  __shared__ double sdd[4];
  __shared__ float swf[8];
  __shared__ int swi[8];
  __shared__ float swp[4];
  __shared__ float spitch[PSTG];
  __shared__ int rsA[RCAP], rsB[RCAP], rsT[RCAP], rLA[RCAP], rRA[RCAP];
  __shared__ int m0sh;
  int tid = threadIdx.x;
  int lane = tid & 63, wv = tid >> 6;
  if (scal[3] == 0u) return;
  int ns0 = min((int)scal[8], RCAP), ne0 = min((int)scal[9], RCAP);
  if (tid < ns0) rsA[tid] = s0l[tid];
  if (tid < ne0) rsB[tid] = e0l[tid];
  bool useL = (S <= PSTG);
  if (useL) { for (int k = tid; k < S; k += NTW) spitch[k] = pitch[k]; }
  __syncthreads();
  ranksort(rsA, ns0, tid, rsT);
  ranksort(rsB, ne0, tid, rsT);
  float f0_1 = (T > 1) ? __uint_as_float(scal[16]) : 0.0f;
  if (tid == 0) m0sh = pair_regions_lds(f0_1, T, rsA, ns0, rsB, ne0, rLA, rRA);
  __syncthreads();
  int nreg = m0sh;
  double rr = (double)S / (double)T;
  float gp = __uint_as_float(scal[0]);
  for (int wid = blockIdx.x; wid < 2 * nreg; wid += gridDim.x) {
    int r = wid >> 1;
    bool rightdir = (wid & 1) != 0;
    int left = rLA[r], right = rRA[r];
    int middle = (left + right) >> 1;
    // ---- stage snd + w windows for this task ----
    int wb0 = left - 1024; if (wb0 < 0) wb0 = 0;
    int wb1 = right + 1024; if (wb1 > T) wb1 = T;
    bool useW = (wb1 - wb0) <= SNDW;
    __syncthreads();  // protect prev task's lsnd/refp/swf reads
    if (useW) {
      for (int k = tid; k < wb1 - wb0; k += NTW) {
        lsnd[k] = snd[wb0 + k];
        swtab[k] = (short)w0[wb0 + k];
      }
    }
    __syncthreads();  // staging visible
    double fm = useL ? (double)interp1(spitch, S, rr, middle) : (double)interp1(pitch, S, rr, middle);
    double wd = SRATE / fm;
    long long wcap = 2LL * (long long)T;
    int w = (wd >= (double)wcap) ? (int)wcap : (int)wd;
    if (w < 1) w = 1;
    int s0 = middle - w / 2; if (s0 < 0) s0 = 0;
    int wlen = w; if (wlen > T - s0) wlen = T - s0;
    float lmn = FLT_MAX; int lmni = INT_MAX;
    float lmx = -FLT_MAX; int lmxi = INT_MAX;
    for (int k = tid; k < wlen; k += NTW) {
      int idx = s0 + k;
      float v = (useW && idx >= wb0 && idx < wb1) ? lsnd[idx - wb0] : snd[idx];
      if (v < lmn) { lmn = v; lmni = k; }
      if (v > lmx) { lmx = v; lmxi = k; }
    }
    for (int off = 32; off; off >>= 1) {
      float ov = __shfl_xor(lmn, off, 64); int oi = __shfl_xor(lmni, off, 64);
      if (ov < lmn || (ov == lmn && oi < lmni)) { lmn = ov; lmni = oi; }
      float ov2 = __shfl_xor(lmx, off, 64); int oi2 = __shfl_xor(lmxi, off, 64);
      if (ov2 > lmx || (ov2 == lmx && oi2 < lmxi)) { lmx = ov2; lmxi = oi2; }
    }
    if (lane == 0) { swf[wv] = lmn; swi[wv] = lmni; swf[4 + wv] = lmx; swi[4 + wv] = lmxi; }
    __syncthreads();
    float mn = swf[0]; int imn = swi[0];
    float mx = swf[4]; int imx = swi[4];
    for (int q = 1; q < 4; q++) {
      float ov = swf[q]; int oi = swi[q];
      if (ov < mn || (ov == mn && oi < imn)) { mn = ov; imn = oi; }
      float ov2 = swf[4 + q]; int oi2 = swi[4 + q];
      if (ov2 > mx || (ov2 == mx && oi2 < imx)) { mx = ov2; imx = oi2; }
    }
    __syncthreads();
    int i;
    if (mn == mx) i = middle;
    else i = s0 + ((fabsf(mn) > fabsf(mx)) ? imn : imx);
    if (!rightdir) {
      int nl = 0, guard = 0;
      for (;;) {
        if (++guard > 500000) break;
        int wcur;
        if (useW && i >= wb0 && i < wb1) wcur = (int)swtab[i - wb0];
        else {
          double fi = useL ? (double)interp1(spitch, S, rr, i) : (double)interp1(pitch, S, rr, i);
          if (fi < 60.0) fi = 60.0;
          int ww = (int)(SRATE / fi); if (ww < 1) ww = 1; if (ww > WMAX - 1) ww = WMAX - 1;
          wcur = ww;
        }
        FPRes p = find_peak_block(snd, lsnd, wb0, wb1, useW, T, i, wcur, false, tid,
                                  refp, sdd, swf, swi, swp);
        i = p.i;
        if (p.corr == -1.0f) i -= p.w;
        if (i < left) {
          if ((double)p.corr > 0.7 && (double)p.peak > 0.023333 * (double)gp) {
            if (nl < LCR) { if (tid == 0) lcand[r * LCR + nl] = make_int2(i, p.w); nl++; }
          }
          break;
        }
        if ((double)p.corr > 0.3 && (p.peak == 0.0f || (double)p.peak > 0.01 * (double)gp)) {
          if (nl < LCR) { if (tid == 0) lcand[r * LCR + nl] = make_int2(i, p.w); nl++; }
        }
      }
      if (tid == 0) lcnt[r] = nl;
    } else {
      int nr = 0, guard = 0;
      for (;;) {
        if (++guard > 500000) break;
        int wcur;
        if (useW && i >= wb0 && i < wb1) wcur = (int)swtab[i - wb0];
        else {
          double fi = useL ? (double)interp1(spitch, S, rr, i) : (double)interp1(pitch, S, rr, i);
          if (fi < 60.0) fi = 60.0;
          int ww = (int)(SRATE / fi); if (ww < 1) ww = 1; if (ww > WMAX - 1) ww = WMAX - 1;
          wcur = ww;
        }
        FPRes p = find_peak_block(snd, lsnd, wb0, wb1, useW, T, i, wcur, true, tid,
                                  refp, sdd, swf, swi, swp);
        i = p.i;
        if (p.corr == -1.0f) i += p.w;
        if (i >= right) {
          if ((double)p.corr > 0.7 && (double)p.peak > 0.023333 * (double)gp) {
            if (nr < RCR) { if (tid == 0) rpk[r * RCR + nr] = i; nr++; }
          }
          break;
        }
        if ((double)p.corr > 0.3 && (p.peak == 0.0f || (double)p.peak > 0.01 * (double)gp)) {
          if (nr < RCR) { if (tid == 0) rpk[r * RCR + nr] = i; nr++; }
        }
      }
      if (tid == 0) rcnt[r] = nr;
    }
  }
}

// ---- fused merge+plan: one BLOCK (256 thr) per r1-region. Each block
// redundantly (a) computes BOTH region pairings in-block (replicated
// kregsort2), (b) performs the merge (ballot-prefix filter+copy, identical
// positions/order/values to the serial reference) directly into LDS sp[],
// (c) sorted-check + bitonic fallback (ib as scratch) + clip, then (d) the
// serial plan with the register-windowed peak pointer. Eliminates the kmerge
// and kregsort2 launches and the global peaks round-trip. ----
__global__ __launch_bounds__(256) void kplan(const int* __restrict__ pd, int T, unsigned* scal,
                                             const int2* __restrict__ lcand, const int* __restrict__ lcnt,
                                             const int* __restrict__ rpk, const int* __restrict__ rcnt,
                                             const int* __restrict__ s0l, const int* __restrict__ e0l,
                                             const int* __restrict__ s1l, const int* __restrict__ e1l,
                                             int4* __restrict__ ops, int* __restrict__ opcnt) {
  __shared__ int sp[SCAP];
  __shared__ int ib[FCAP];
  __shared__ int rsA[RCAP], rsB[RCAP], rsT[RCAP], rLA[RCAP], rRA[RCAP];
  __shared__ long long arR[RCAP];
  __shared__ long long lastR[RCAP];
  __shared__ int rcs[RCAP], lcs[RCAP], klc[RCAP], off[RCAP + 1];
  __shared__ int m0sh, m1sh, unsorted;
  int tid = threadIdx.x;
  int lane = tid & 63, wv = tid >> 6;  // 4 waves
  int r = (int)blockIdx.x;
  if (scal[3] == 0u) {
    if (r == 0 && tid == 0) { scal[6] = 0u; scal[14] = 0u; }
    return;
  }
  int ns0 = min((int)scal[8], RCAP), ne0 = min((int)scal[9], RCAP);
  int ns1 = min((int)scal[10], RCAP), ne1 = min((int)scal[11], RCAP);
  float f0_1 = (T > 1) ? __uint_as_float(scal[16]) : 0.0f;
  float f0s_1 = (T > 1) ? __uint_as_float(scal[17]) : 0.0f;
  // pairing 0 (only the count nreg0 is needed by the merge)
  if (tid < ns0) rsA[tid] = s0l[tid];
  if (tid < ne0) rsB[tid] = e0l[tid];
  __syncthreads();
  ranksort(rsA, ns0, tid, rsT);
  ranksort(rsB, ne0, tid, rsT);
  if (tid == 0) m0sh = pair_regions_lds(f0_1, T, rsA, ns0, rsB, ne0, rLA, rRA);
  __syncthreads();
  int nreg0 = m0sh;
  // pairing 1 (overwrites rLA/rRA with the f0s regions used for planning)
  if (tid < ns1) rsA[tid] = s1l[tid];
  if (tid < ne1) rsB[tid] = e1l[tid];
  __syncthreads();
  ranksort(rsA, ns1, tid, rsT);
  ranksort(rsB, ne1, tid, rsT);
  if (tid == 0) m1sh = pair_regions_lds(f0s_1, T, rsA, ns1, rsB, ne1, rLA, rRA);
  __syncthreads();
  int nreg1 = m1sh;
  // ---- merge into sp (redundant per block; value-exact) ----
  int npk = 0;
  if (nreg0 > 0) {
    if (tid < nreg0) {
      int rc = rcnt[tid];
      rcs[tid] = rc;
      lcs[tid] = lcnt[tid];
      lastR[tid] = (rc > 0) ? (long long)rpk[tid * RCR + rc - 1] : LLONG_MIN;
    }
    __syncthreads();
    if (tid == 0) {
      long long ar = -(1LL << 62);
      for (int q = 0; q < nreg0; q++) { arR[q] = ar; if (rcs[q] > 0) ar = lastR[q]; }
    }
    __syncthreads();
    for (int q = wv; q < nreg0; q += 4) {
      int n = lcs[q];
      long long ar = arR[q];
      int cnt = 0;
      for (int base = 0; base < n; base += 64) {
        int jp = base + lane;
        bool pred = false;
        if (jp < n) {
          int j = n - 1 - jp;
          int2 cd = lcand[q * LCR + j];
          pred = ((double)((long long)cd.x - ar) > 0.8 * (double)cd.y);
        }
        unsigned long long m = __ballot(pred);
        cnt += __popcll(m);
      }
      if (lane == 0) klc[q] = cnt;
    }
    __syncthreads();
    if (tid == 0) {
      int acc = 0;
      for (int q = 0; q < nreg0; q++) { off[q] = acc; acc += klc[q] + rcs[q]; if (acc > SCAP) acc = SCAP; }
      off[nreg0] = acc;
      unsorted = 0;
      if (r == 0) scal[4] = (unsigned)acc;
    }
    __syncthreads();
    for (int q = wv; q < nreg0; q += 4) {
      long long ar = arR[q];
      int n = lcs[q];
      int pos0 = off[q];
      for (int base = 0; base < n; base += 64) {
        int jp = base + lane;
        bool pred = false; int val = 0;
        if (jp < n) {
          int j = n - 1 - jp;
          int2 cd = lcand[q * LCR + j];
          if ((double)((long long)cd.x - ar) > 0.8 * (double)cd.y) { pred = true; val = cd.x; }
        }
        unsigned long long m = __ballot(pred);
        if (pred) {
          int pre = __popcll(m & ((1ull << lane) - 1ull));
          int pos = pos0 + pre;
          if (pos < SCAP) sp[pos] = val;
        }
        pos0 += __popcll(m);
      }
      int rc = rcs[q];
      for (int j = lane; j < rc; j += 64) {
        int pos = pos0 + j;
        if (pos < SCAP) sp[pos] = rpk[q * RCR + j];
      }
    }
    __syncthreads();
    npk = off[nreg0];
    if (npk > 1) {
      for (int k = tid; k < npk - 1; k += 256) {
        if (sp[k] > sp[k + 1]) unsorted = 1;
      }
      __syncthreads();
      if (unsorted) {
        int n2 = 1; while (n2 < npk) n2 <<= 1;
        for (int k = tid; k < n2; k += 256) ib[k] = (k < npk) ? sp[k] : INT_MAX;
        __syncthreads();
        for (int kk = 2; kk <= n2; kk <<= 1) {
          for (int j = kk >> 1; j > 0; j >>= 1) {
            for (int idx = tid; idx < n2; idx += 256) {
              int ixj = idx ^ j;
              if (ixj > idx) {
                int a = ib[idx], b = ib[ixj];
                bool up = ((idx & kk) == 0);
                if ((up && a > b) || (!up && a < b)) { ib[idx] = b; ib[ixj] = a; }
              }
            }
            __syncthreads();
          }
        }
        for (int k = tid; k < npk; k += 256) sp[k] = ib[k];
        __syncthreads();
      }
    }
    for (int k = tid; k < npk; k += 256) { int v = sp[k]; if (v < 0) v = 0; if (v > T - 1) v = T - 1; sp[k] = v; }
    __syncthreads();
  }
  if (npk == 0) {
    if (r == 0 && tid == 0) { scal[6] = 0u; scal[14] = 0u; }
    return;
  }
  if (r == 0 && tid == 0) {
    scal[6] = (nreg1 > 0) ? (unsigned)rRA[nreg1 - 1] : 0u;
    scal[14] = (unsigned)nreg1;
  }
  if (r >= nreg1) return;
  int prev_right = (r == 0) ? 0 : rRA[r - 1];
  int left_v = rLA[r], right_v = rRA[r];
  // stage period window (vectorized int4 with head-peel; ints, bit-exact)
  int span = right_v - left_v;
  int fl_n = span < FCAP ? span : FCAP;
  const int* srcp = pd + left_v;
  int head = (4 - (left_v & 3)) & 3; if (head > fl_n) head = fl_n;
  for (int k = tid; k < head; k += 256) ib[k] = srcp[k];
  int rem4 = (fl_n - head) & ~3;
  for (int k = tid * 4; k < rem4; k += 1024) {
    int4 v = *reinterpret_cast<const int4*>(srcp + head + k);
    ib[head + k] = v.x; ib[head + k + 1] = v.y; ib[head + k + 2] = v.z; ib[head + k + 3] = v.w;
  }
  for (int k = head + rem4 + tid; k < fl_n; k += 256) ib[k] = srcp[k];
  __syncthreads();
  if (tid != 0) return;

  double minpos = (double)__uint_as_float(scal[1]);
  double max_w = 1.25 * SRATE / minpos;
  int c = 0;
  if (prev_right < left_v) {
    ops[r * OPR + c] = make_int4(prev_right, prev_right, left_v - prev_right, left_v - prev_right);
    c++;
  }
  int lv = left_v, guard = 0;
  int lo = -1;  // monotone lower_bound pointer
  int Pm2 = 0, Pm1 = 0, P0 = 0, P1 = 0;  // cached sp[lo-2..lo+1]
  while (lv < right_v) {
    if (++guard > 500000) break;
    int fo = lv - left_v;
    int period = (fo < fl_n) ? ib[fo] : pd[lv];
    int x = lv;
    if (lo < 0) {
      int a = 0, b = npk;
      while (a < b) { int m = (a + b) >> 1; if (sp[m] < x) a = m + 1; else b = m; }
      lo = a;
      Pm2 = (lo - 2 >= 0) ? sp[lo - 2] : 0;
      Pm1 = (lo - 1 >= 0) ? sp[lo - 1] : 0;
      P0  = (lo < npk) ? sp[lo] : 0;
      P1  = (lo + 1 < npk) ? sp[lo + 1] : 0;
    } else {
      while (lo < npk && P0 < x) {
        lo++;
        Pm2 = Pm1; Pm1 = P0; P0 = P1;
        P1 = (lo + 1 < npk) ? sp[lo + 1] : 0;
      }
    }
    long long d0 = (lo > 0) ? (long long)x - (long long)Pm1 : LLONG_MAX;
    long long d1 = (lo < npk) ? (long long)P0 - (long long)x : LLONG_MAX;
    int p, Pp, Ppm1, Pp1;
    if (d0 <= d1) {
      p = lo - 1;
      int tv = Pm1;
      if (p > 0 && Pm2 == tv) {
        while (p > 0 && sp[p - 1] == tv) p--;
        Pp = tv;
        Ppm1 = (p > 0) ? sp[p - 1] : 0;
        Pp1 = (p < npk - 1) ? sp[p + 1] : 0;
      } else {
        Pp = Pm1; Ppm1 = Pm2; Pp1 = P0;
      }
    } else {
      p = lo; Pp = P0; Ppm1 = Pm1; Pp1 = P1;
    }
    int lw = period >> 1, rw = period >> 1;
    if (p > 0) { long long gp_ = (long long)Pp - (long long)Ppm1; if ((double)gp_ <= max_w && gp_ < (long long)lw) lw = (int)gp_; }
    if (p < npk - 1) { long long gp_ = (long long)Pp1 - (long long)Pp; if ((double)gp_ <= max_w && gp_ < (long long)rw) rw = (int)gp_; }
    int left_i = Pp - lw; if (left_i < 0) left_i = 0;
    int right_i = Pp + rw;
    int ival = (right_i - left_i) >> 1;
    if (ival <= 0) break;
    int a0 = lv - ival;
    int len1 = 0;
    if (a0 >= 0) { int e = lv + ival; if (e > T) e = T; len1 = e - a0; if (len1 < 0) len1 = 0; }
    int e2 = left_i + 2 * ival; if (e2 > T) e2 = T;
    int len2 = e2 - left_i; if (len2 < 0) len2 = 0;
    int seglen = len1 < len2 ? len1 : len2;
    int len_dst = (a0 < 0) ? 0 : ((T - a0 < seglen) ? T - a0 : seglen);
    int len_src = (T - left_i < seglen) ? T - left_i : seglen;
    int L = seglen; if (len_dst < L) L = len_dst; if (len_src < L) L = len_src;
    if (L > 0 && c < OPR) { ops[r * OPR + c] = make_int4(a0, left_i, L, 2 * ival); c++; }
    lv += 2 * ival;
  }
  opcnt[r] = c;
}

// ---- fused output: overlap-add scatter (guarded to dst < tail) + tail copy ----
__global__ __launch_bounds__(256) void kout(const float* __restrict__ snd, float* __restrict__ out,
                                            const unsigned* scal, const int4* __restrict__ ops,
                                            const int* __restrict__ opcnt, int T) {
  int tail = (int)scal[6];
  if (blockIdx.x < APPLYB) {
    int nreg = (int)scal[14];
    int total = nreg * OPR;
    for (int slot = blockIdx.x; slot < total; slot += APPLYB) {
      int r = slot / OPR, j = slot - r * OPR;
      if (j >= opcnt[r]) continue;
      int4 o = ops[r * OPR + j];
      double nn = (double)o.w;
      int kend = o.z;
      { int lim = tail - o.x; if (lim < 0) lim = 0; if (kend > lim) kend = lim; }
      for (int k = threadIdx.x; k < kend; k += blockDim.x) {
        double cph = (6.283185307179586 * (double)k) / nn;
        float wv = (float)(0.5 - 0.5 * cos(cph));
        atomicAdd(out + o.x + k, __fmul_rn(wv, snd[o.y + k]));
      }
    }
  } else {
    int b = blockIdx.x - APPLYB;
    int stride = TAILB * 256;
    for (int t = b * 256 + threadIdx.x; t < T; t += stride)
      if (t >= tail) out[t] = snd[t];
  }
}

extern "C" void kernel_launch(void* const* d_in, const int* in_sizes, int n_in,
                              void* d_out, int out_size, void* d_ws, size_t ws_size,
                              hipStream_t stream) {
  (void)n_in; (void)ws_size;
  int T = in_sizes[0];
  int S = in_sizes[1];
  const float* snd = (const float*)d_in[0];
  const float* pitch = (const float*)d_in[1];
  const int* steps = (const int*)d_in[2];
  const float* prange = (const float*)d_in[3];
  float* out = (float*)d_out;

  char* base = (char*)d_ws;
  size_t off = 0;
  auto alloc = [&](size_t bytes, size_t align) -> char* {
    off = (off + align - 1) & ~(align - 1);
    char* p = base + off;
    off += bytes;
    return p;
  };
  int* pd    = (int*)alloc((size_t)T * 4, 16);
  int* w0    = (int*)alloc((size_t)T * 4, 16);
  unsigned* scal = (unsigned*)alloc(256, 16);
  int* s0l = (int*)alloc(RCAP * 4, 4);
  int* e0l = (int*)alloc(RCAP * 4, 4);
  int* s1l = (int*)alloc(RCAP * 4, 4);
  int* e1l = (int*)alloc(RCAP * 4, 4);
  int* lcnt = (int*)alloc(RCAP * 4, 4);
  int* rcnt = (int*)alloc(RCAP * 4, 4);
  int* opcnt = (int*)alloc(RCAP * 4, 4);
  int2* lcand = (int2*)alloc((size_t)RCAP * LCR * 8, 8);
  int* rpk = (int*)alloc((size_t)RCAP * RCR * 4, 4);
  int4* ops = (int4*)alloc((size_t)RCAP * OPR * 16, 16);

  hipMemsetAsync(d_out, 0, (size_t)out_size * sizeof(float), stream);
  kstats<<<1, 256, 0, stream>>>(pitch, S, scal);
  kprep<<<1024, 256, 0, stream>>>(pitch, S, T, snd, scal, steps, prange, pd, w0, s0l, e0l, s1l, e1l);
  kwalk<<<256, NTW, 0, stream>>>(snd, pitch, S, w0, T, scal, s0l, e0l, lcand, lcnt, rpk, rcnt);
  kplan<<<RCAP, 256, 0, stream>>>(pd, T, scal, lcand, lcnt, rpk, rcnt, s0l, e0l, s1l, e1l, ops, opcnt);
  kout<<<APPLYB + TAILB, 256, 0, stream>>>(snd, out, scal, ops, opcnt, T);
}

// Round 13
// 457.881 us; speedup vs baseline: 1.0278x; 1.0278x over previous
//
#include <hip/hip_runtime.h>
#include <cfloat>
#include <climits>
#include <math.h>

#define SRATE 22050.0
#define WMAX 512
#define RCAP 128
#define LCR 256
#define RCR 512
#define SCAP 16384
#define OPR 256
#define MSL 3072
#define NTW 256
#define NTM 1024
#define PCAP 8192
#define FCAP 16384
#define PSTG 4096
#define SNDW 15872
#define RPW 136
#define APPLYB 2048
#define TAILB 1024

// scal layout: 0 gp_bits, 1 minpos_bits, 2 median_bits, 3 has_pos, 4 n_peaks,
// 6 tail, 8 ns0, 9 ne0, 10 ns1, 11 ne1, 12 nreg0, 13 nreg1, 14 nreg1_eff,
// 15 n_pos, 16 f0[1] bits, 17 f0s[1] bits

// ---- fused stats: scal init + positive count/flag + radix-select median ----
__global__ __launch_bounds__(256) void kstats(const float* __restrict__ pitch, int S, unsigned* scal) {
  __shared__ float sp[MSL];
  __shared__ int sc[256];
  __shared__ int sa[256];
  __shared__ unsigned hist[256];
  __shared__ unsigned sprefix, smask;
  __shared__ int srank;
  int tid = threadIdx.x;
  if (tid < 64) scal[tid] = (tid == 1) ? 0x7f800000u : 0u;
  bool lds = (S <= MSL);
  int c = 0, a = 0;
  for (int j = tid; j < S; j += 256) {
    float v = pitch[j];
    if (lds) sp[j] = v;
    if (v > 0.0f) c++;
    if (v > 1e-05f) a = 1;
  }
  sc[tid] = c; sa[tid] = a; __syncthreads();
  for (int st = 128; st; st >>= 1) {
    if (tid < st) { sc[tid] += sc[tid + st]; sa[tid] |= sa[tid + st]; }
    __syncthreads();
  }
  int n = sc[0];
  if (tid == 0) { scal[15] = (unsigned)n; scal[3] = (unsigned)sa[0]; }
  if (n == 0) return;
  if (tid == 0) { sprefix = 0u; smask = 0u; srank = (n - 1) >> 1; }
  __syncthreads();
  for (int shift = 24; shift >= 0; shift -= 8) {
    hist[tid] = 0u;
    __syncthreads();
    unsigned pfx = sprefix, msk = smask;
    for (int q = tid; q < S; q += 256) {
      float v = lds ? sp[q] : pitch[q];
      if (v > 0.0f) {
        unsigned u = __float_as_uint(v);
        if ((u & msk) == pfx) atomicAdd(&hist[(u >> shift) & 255u], 1u);
      }
    }
    __syncthreads();
    if (tid == 0) {
      int r = srank;
      unsigned b = 0;
      for (;;) { unsigned cc = hist[b]; if (r < (int)cc) break; r -= (int)cc; b++; }
      srank = r;
      sprefix = pfx | (b << shift);
      smask = msk | (0xFFu << shift);
    }
    __syncthreads();
  }
  if (tid == 0) scal[2] = sprefix;
}

__device__ __forceinline__ float interp1(const float* __restrict__ pitch, int S, double r, int t) {
  double x = ((double)t + 0.5) * r - 0.5;
  if (x < 0.0) x = 0.0;
  double sm1 = (double)(S - 1);
  if (x > sm1) x = sm1;
  double fl = floor(x);
  int i0 = (int)fl;
  int i1 = i0 + 1; if (i1 > S - 1) i1 = S - 1;
  float f = (float)(x - fl);
  return __fadd_rn(__fmul_rn(pitch[i0], __fsub_rn(1.0f, f)), __fmul_rn(pitch[i1], f));
}

// ---- fused: f0s-derived tables (pd, w0), gp, minpos, region transitions.
// f0/f0s arrays not materialized: only elements [1] were ever read
// (kregsort2) -> passed via scal[16]/[17]. interp1(t-1) comes from lane-1
// via __shfl_up (identical value by construction; lane 0 computes directly;
// active lanes form a prefix per iteration so shfl is well-defined). ----
__global__ __launch_bounds__(256) void kprep(const float* __restrict__ pitch, int S, int T,
                                             const float* __restrict__ snd, unsigned* scal,
                                             const int* __restrict__ steps_p, const float* __restrict__ pr_p,
                                             int* __restrict__ pd, int* __restrict__ w0,
                                             int* s0l, int* e0l, int* s1l, int* e1l) {
  __shared__ float smax[256];
  __shared__ unsigned smin[256];
  float med = __uint_as_float(scal[2]);
  double factor = exp2((double)steps_p[0] / 12.0);
  float fac32 = (float)factor;
  float m32 = (float)((double)med * factor);
  float pr32 = pr_p[0];
  double r = (double)S / (double)T;
  float amax = 0.0f;
  unsigned lmin = 0x7f800000u;
  int lane = threadIdx.x & 63;
  int stride = gridDim.x * blockDim.x;
  for (int t = blockIdx.x * blockDim.x + threadIdx.x; t < T; t += stride) {
    float v = interp1(pitch, S, r, t);
    float v1 = __fmul_rn(v, fac32);
    float vs = 0.0f;
    if (v1 > 0.0f) vs = __fadd_rn(m32, __fmul_rn(__fsub_rn(v1, m32), pr32));
    if (t == 1) { scal[16] = __float_as_uint(v); scal[17] = __float_as_uint(vs); }
    { double fd = (double)vs; if (fd < 60.0) fd = 60.0; pd[t] = (int)(SRATE / fd); }
    { double fi = (double)v; if (fi < 60.0) fi = 60.0;
      int ww = (int)(SRATE / fi); if (ww < 1) ww = 1; if (ww > WMAX - 1) ww = WMAX - 1;
      w0[t] = ww; }
    if (vs > 0.0f) { unsigned b = __float_as_uint(vs); if (b < lmin) lmin = b; }
    float a = fabsf(snd[t]); if (a > amax) amax = a;
    bool pv = false, pv1 = false;
    float upv = __shfl_up(v, 1, 64);
    if (t > 0) {
      float pvv = (lane == 0) ? interp1(pitch, S, r, t - 1) : upv;
      pv = pvv > 0.0f;
      float pm1 = __fmul_rn(pvv, fac32);
      float pvs = 0.0f;
      if (pm1 > 0.0f) pvs = __fadd_rn(m32, __fmul_rn(__fsub_rn(pm1, m32), pr32));
      pv1 = pvs > 0.0f;
    }
    bool cv = v > 0.0f, cv1 = vs > 0.0f;
    if (cv && (t == 0 || !pv))  { unsigned k = atomicAdd(scal + 8, 1u);  if (k < RCAP) s0l[k] = t; }
    if (!cv && t > 0 && pv)     { unsigned k = atomicAdd(scal + 9, 1u);  if (k < RCAP) e0l[k] = t; }
    if (cv1 && (t == 0 || !pv1)){ unsigned k = atomicAdd(scal + 10, 1u); if (k < RCAP) s1l[k] = t; }
    if (!cv1 && t > 0 && pv1)   { unsigned k = atomicAdd(scal + 11, 1u); if (k < RCAP) e1l[k] = t; }
  }
  smax[threadIdx.x] = amax; smin[threadIdx.x] = lmin; __syncthreads();
  for (int st = 128; st; st >>= 1) {
    if (threadIdx.x < st) {
      float o = smax[threadIdx.x + st]; if (o > smax[threadIdx.x]) smax[threadIdx.x] = o;
      unsigned u = smin[threadIdx.x + st]; if (u < smin[threadIdx.x]) smin[threadIdx.x] = u;
    }
    __syncthreads();
  }
  if (threadIdx.x == 0) {
    atomicMax(scal + 0, __float_as_uint(smax[0]));
    atomicMin(scal + 1, smin[0]);
  }
}

// parallel rank sort (distinct values) in LDS
__device__ void ranksort(int* a, int n, int tid, int* tmp) {
  int v = 0, rk = 0;
  if (tid < n) {
    v = a[tid];
    for (int q = 0; q < n; q++) if (a[q] < v) rk++;
  }
  __syncthreads();
  if (tid < n) tmp[rk] = v;
  __syncthreads();
  if (tid < n) a[tid] = tmp[tid];
  __syncthreads();
}

// pairing over LDS arrays; reproduces repeated _find_voiced semantics
__device__ int pair_regions_lds(float f1, int T, int* sl, int ns, int* el, int ne, int* L, int* R) {
  int b = 0;
  if (ns > 0 && sl[0] == 0) {
    if (T > 1 && f1 > 0.0f) sl[0] = 1;
    else b = 1;
  }
  int m = 0, j = 0;
  for (int k = b; k < ns; k++) {
    int Lv = sl[k];
    while (j < ne && el[j] <= Lv) j++;
    int Rv = (j < ne) ? el[j] : T;
    if (m < RCAP) { L[m] = Lv; R[m] = Rv; m++; }
  }
  return m;
}

__global__ __launch_bounds__(128) void kregsort2(int T, unsigned* scal,
                                                 const int* __restrict__ s0l, const int* __restrict__ e0l,
                                                 const int* __restrict__ s1l, const int* __restrict__ e1l,
                                                 int* r0L, int* r0R, int* r1L, int* r1R) {
  __shared__ int A[RCAP], B[RCAP], C[RCAP], D[RCAP];
  __shared__ int tmp[RCAP];
  __shared__ int LA[RCAP], RA[RCAP];
  int tid = threadIdx.x;
  int ns0 = min((int)scal[8], RCAP), ne0 = min((int)scal[9], RCAP);
  int ns1 = min((int)scal[10], RCAP), ne1 = min((int)scal[11], RCAP);
  if (tid < ns0) A[tid] = s0l[tid];
  if (tid < ne0) B[tid] = e0l[tid];
  if (tid < ns1) C[tid] = s1l[tid];
  if (tid < ne1) D[tid] = e1l[tid];
  __syncthreads();
  ranksort(A, ns0, tid, tmp);
  ranksort(B, ne0, tid, tmp);
  ranksort(C, ns1, tid, tmp);
  ranksort(D, ne1, tid, tmp);
  float f0_1 = (T > 1) ? __uint_as_float(scal[16]) : 0.0f;
  float f0s_1 = (T > 1) ? __uint_as_float(scal[17]) : 0.0f;
  __shared__ int m0s, m1s;
  if (tid == 0) {
    m0s = pair_regions_lds(f0_1, T, A, ns0, B, ne0, LA, RA);
  }
  __syncthreads();
  if (tid < m0s) { r0L[tid] = LA[tid]; r0R[tid] = RA[tid]; }
  __syncthreads();
  if (tid == 0) {
    m1s = pair_regions_lds(f0s_1, T, C, ns1, D, ne1, LA, RA);
  }
  __syncthreads();
  if (tid < m1s) { r1L[tid] = LA[tid]; r1R[tid] = RA[tid]; }
  if (tid == 0) { scal[12] = (unsigned)m0s; scal[13] = (unsigned)m1s; }
}

struct FPRes { int w; int i; float corr; float peak; };
struct FPG { int w, s, cl, nw, rlen; bool ok; };

// geometry from a precomputed (already clamped) window length w
__device__ __forceinline__ FPG fp_geom(int T, int i, int w, bool right_dir) {
  FPG g;
  int s = i - w / 2; if (s < 0) s = 0;
  int cl, cr;
  if (right_dir) {
    cl = (int)((double)i + 0.3 * (double)w);
    cr = (int)((double)i + 0.75 * (double)w);
  } else {
    double al = (double)i - 1.75 * (double)w;
    double bl = (double)i - 1.3 * (double)w;
    cl = (int)al; if (cl < 0) cl = 0;
    cr = (int)bl; if (cr < 0) cr = 0;
  }
  g.w = w; g.s = s; g.cl = cl;
  g.ok = !(cl == cr || T - cl < w);
  int nw = (((cr + w) < T ? (cr + w) : T)) - cl - w + 1;
  if (nw < 1) nw = 1;
  g.nw = nw;
  int rlen = T - s; if (rlen > w) rlen = w;
  g.rlen = rlen;
  return g;
}

// r7 fp_impl (proven): 2 barriers, deinterleaved ref (ds_read_b128, RPW=136),
// trimmed argmax.
template <bool L>
__device__ __forceinline__ FPRes fp_impl(const float* __restrict__ snd, const float* lsnd, int wb0,
                                         FPG g, int i, int tid,
                                         float (*refp)[RPW], double* sdd, float* swf, int* swi, float* swp) {
  FPRes res;
  int w = g.w, s = g.s, cl = g.cl, nw = g.nw, rlen = g.rlen;
  res.w = w;
  int lane = tid & 63, wv = tid >> 6;
  // stage ref (deinterleaved) + ref norm^2 (barrier 1 covers refp and sdd)
  double part = 0.0;
  for (int k = tid; k < w; k += NTW) {
    float v = (k < rlen) ? (L ? lsnd[s + k - wb0] : snd[s + k]) : 0.0f;
    refp[k & 3][k >> 2] = v;
    part += (double)v * (double)v;
  }
  for (int off = 32; off; off >>= 1) part += __shfl_xor(part, off, 64);
  if (lane == 0) sdd[wv] = part;
  __syncthreads();  // barrier 1
  double refden = sqrt(sdd[0] + sdd[1] + sdd[2] + sdd[3]);
  if (refden < 1e-12) refden = 1e-12;
  // candidates: group g = tid>>2 (64 groups), sub-lane = tid&3
  int gg = tid >> 2, sub = tid & 3;
  float bestv = -FLT_MAX; int bestr = INT_MAX; float bestp = 0.0f;
  for (int base = 0; base < nw; base += 64) {
    int r = base + gg;
    if (r < nw) {
      const float* seg = (L ? (lsnd + (cl - wb0)) : (snd + cl)) + r;
      const float* rrow = refp[sub];
      double d0 = 0.0, d1 = 0.0, n0 = 0.0, n1 = 0.0;
      float pkc = 0.0f;
      int k = sub, j = 0;
      for (; k + 12 < w; k += 16, j += 4) {
        float4 rv = *reinterpret_cast<const float4*>(rrow + j);
        float a0f = seg[k], a1f = seg[k + 4];
        pkc = fmaxf(pkc, fabsf(a0f));
        pkc = fmaxf(pkc, fabsf(a1f));
        double a0 = (double)a0f, a1 = (double)a1f;
        d0 += a0 * (double)rv.x; n0 += a0 * a0;
        d1 += a1 * (double)rv.y; n1 += a1 * a1;
        float a2f = seg[k + 8], a3f = seg[k + 12];
        pkc = fmaxf(pkc, fabsf(a2f));
        pkc = fmaxf(pkc, fabsf(a3f));
        double a2 = (double)a2f, a3 = (double)a3f;
        d0 += a2 * (double)rv.z; n0 += a2 * a2;
        d1 += a3 * (double)rv.w; n1 += a3 * a3;
      }
      for (; k + 4 < w; k += 8) {
        float a0f = seg[k], a1f = seg[k + 4];
        pkc = fmaxf(pkc, fabsf(a0f));
        pkc = fmaxf(pkc, fabsf(a1f));
        double a0 = (double)a0f, b0 = (double)refp[k & 3][k >> 2];
        double a1 = (double)a1f, b1 = (double)refp[(k + 4) & 3][(k + 4) >> 2];
        d0 += a0 * b0; n0 += a0 * a0;
        d1 += a1 * b1; n1 += a1 * a1;
      }
      for (; k < w; k += 4) {
        float af = seg[k];
        pkc = fmaxf(pkc, fabsf(af));
        double a = (double)af; d0 += a * (double)refp[k & 3][k >> 2]; n0 += a * a;
      }
      double dot = d0 + d1, nr2 = n0 + n1;
      dot += __shfl_xor(dot, 1, 64); nr2 += __shfl_xor(nr2, 1, 64);
      pkc = fmaxf(pkc, __shfl_xor(pkc, 1, 64));
      dot += __shfl_xor(dot, 2, 64); nr2 += __shfl_xor(nr2, 2, 64);
      pkc = fmaxf(pkc, __shfl_xor(pkc, 2, 64));
      if (sub == 0) {
        double den = sqrt(nr2); if (den < 1e-12) den = 1e-12;
        float c = (float)(dot / (den * refden));
        if (c > bestv) { bestv = c; bestr = r; bestp = pkc; }
      }
    }
  }
  // wave argmax over sub==0 lanes: levels 32..4 only (low-2-bit lanes never mix)
  for (int off = 32; off >= 4; off >>= 1) {
    float ov = __shfl_xor(bestv, off, 64);
    int orr = __shfl_xor(bestr, off, 64);
    float op = __shfl_xor(bestp, off, 64);
    if (ov > bestv || (ov == bestv && orr < bestr)) { bestv = ov; bestr = orr; bestp = op; }
  }
  if (lane == 0) { swf[wv] = bestv; swi[wv] = bestr; swp[wv] = bestp; }
  __syncthreads();  // barrier 2
  float bv = swf[0]; int br = swi[0]; float bp = swp[0];
  for (int q = 1; q < 4; q++) {
    float ov = swf[q]; int orr = swi[q]; float op = swp[q];
    if (ov > bv || (ov == bv && orr < br)) { bv = ov; br = orr; bp = op; }
  }
  res.corr = bv;
  res.i = i + (br + cl) - s;
  res.peak = bp;
  return res;
}

__device__ __forceinline__ FPRes find_peak_block(const float* __restrict__ snd,
                                                 const float* lsnd, int wb0, int wb1, bool useW,
                                                 int T, int i, int wcur, bool right_dir, int tid,
                                                 float (*refp)[RPW], double* sdd,
                                                 float* swf, int* swi, float* swp) {
  FPG g = fp_geom(T, i, wcur, right_dir);
  if (!g.ok) { FPRes r; r.w = g.w; r.corr = -1.0f; r.i = i; r.peak = 0.0f; return r; }
  int lo_a = g.s < g.cl ? g.s : g.cl;
  int hi1 = g.s + g.w, hi2 = g.cl + g.nw + g.w;
  int hi_a = hi1 > hi2 ? hi1 : hi2;
  bool inW = useW && lo_a >= wb0 && hi_a <= wb1;
  if (inW) return fp_impl<true>(snd, lsnd, wb0, g, i, tid, refp, sdd, swf, swi, swp);
  return fp_impl<false>(snd, lsnd, wb0, g, i, tid, refp, sdd, swf, swi, swp);
}

// ---- walks: one block (256 threads) per (region, direction) ----
__global__ __launch_bounds__(NTW) void kwalk(const float* __restrict__ snd,
                                             const float* __restrict__ pitch, int S,
                                             const int* __restrict__ w0,
                                             int T, const unsigned* scal,
                                             const int* __restrict__ r0L, const int* __restrict__ r0R,
                                             int2* __restrict__ lcand, int* __restrict__ lcnt,
                                             int* __restrict__ rpk, int* __restrict__ rcnt) {
  __shared__ float lsnd[SNDW];
  __shared__ short swtab[SNDW];
  __shared__ __align__(16) float refp[4][RPW];
  __shared__ double sdd[4];
  __shared__ float swf[8];
  __shared__ int swi[8];
  __shared__ float swp[4];
  __shared__ float spitch[PSTG];
  int tid = threadIdx.x;
  int lane = tid & 63, wv = tid >> 6;
  if (scal[3] == 0u) return;
  bool useL = (S <= PSTG);
  if (useL) { for (int k = tid; k < S; k += NTW) spitch[k] = pitch[k]; }
  __syncthreads();
  double rr = (double)S / (double)T;
  int nreg = (int)scal[12];
  float gp = __uint_as_float(scal[0]);
  for (int wid = blockIdx.x; wid < 2 * nreg; wid += gridDim.x) {
    int r = wid >> 1;
    bool rightdir = (wid & 1) != 0;
    int left = r0L[r], right = r0R[r];
    int middle = (left + right) >> 1;
    // ---- stage snd + w windows for this task ----
    int wb0 = left - 1024; if (wb0 < 0) wb0 = 0;
    int wb1 = right + 1024; if (wb1 > T) wb1 = T;
    bool useW = (wb1 - wb0) <= SNDW;
    __syncthreads();  // protect prev task's lsnd/refp/swf reads
    if (useW) {
      for (int k = tid; k < wb1 - wb0; k += NTW) {
        lsnd[k] = snd[wb0 + k];
        swtab[k] = (short)w0[wb0 + k];
      }
    }
    __syncthreads();  // staging visible
    double fm = useL ? (double)interp1(spitch, S, rr, middle) : (double)interp1(pitch, S, rr, middle);
    double wd = SRATE / fm;
    long long wcap = 2LL * (long long)T;
    int w = (wd >= (double)wcap) ? (int)wcap : (int)wd;
    if (w < 1) w = 1;
    int s0 = middle - w / 2; if (s0 < 0) s0 = 0;
    int wlen = w; if (wlen > T - s0) wlen = T - s0;
    float lmn = FLT_MAX; int lmni = INT_MAX;
    float lmx = -FLT_MAX; int lmxi = INT_MAX;
    for (int k = tid; k < wlen; k += NTW) {
      int idx = s0 + k;
      float v = (useW && idx >= wb0 && idx < wb1) ? lsnd[idx - wb0] : snd[idx];
      if (v < lmn) { lmn = v; lmni = k; }
      if (v > lmx) { lmx = v; lmxi = k; }
    }
    for (int off = 32; off; off >>= 1) {
      float ov = __shfl_xor(lmn, off, 64); int oi = __shfl_xor(lmni, off, 64);
      if (ov < lmn || (ov == lmn && oi < lmni)) { lmn = ov; lmni = oi; }
      float ov2 = __shfl_xor(lmx, off, 64); int oi2 = __shfl_xor(lmxi, off, 64);
      if (ov2 > lmx || (ov2 == lmx && oi2 < lmxi)) { lmx = ov2; lmxi = oi2; }
    }
    if (lane == 0) { swf[wv] = lmn; swi[wv] = lmni; swf[4 + wv] = lmx; swi[4 + wv] = lmxi; }
    __syncthreads();
    float mn = swf[0]; int imn = swi[0];
    float mx = swf[4]; int imx = swi[4];
    for (int q = 1; q < 4; q++) {
      float ov = swf[q]; int oi = swi[q];
      if (ov < mn || (ov == mn && oi < imn)) { mn = ov; imn = oi; }
      float ov2 = swf[4 + q]; int oi2 = swi[4 + q];
      if (ov2 > mx || (ov2 == mx && oi2 < imx)) { mx = ov2; imx = oi2; }
    }
    __syncthreads();
    int i;
    if (mn == mx) i = middle;
    else i = s0 + ((fabsf(mn) > fabsf(mx)) ? imn : imx);
    if (!rightdir) {
      int nl = 0, guard = 0;
      for (;;) {
        if (++guard > 500000) break;
        int wcur;
        if (useW && i >= wb0 && i < wb1) wcur = (int)swtab[i - wb0];
        else {
          double fi = useL ? (double)interp1(spitch, S, rr, i) : (double)interp1(pitch, S, rr, i);
          if (fi < 60.0) fi = 60.0;
          int ww = (int)(SRATE / fi); if (ww < 1) ww = 1; if (ww > WMAX - 1) ww = WMAX - 1;
          wcur = ww;
        }
        FPRes p = find_peak_block(snd, lsnd, wb0, wb1, useW, T, i, wcur, false, tid,
                                  refp, sdd, swf, swi, swp);
        i = p.i;
        if (p.corr == -1.0f) i -= p.w;
        if (i < left) {
          if ((double)p.corr > 0.7 && (double)p.peak > 0.023333 * (double)gp) {
            if (nl < LCR) { if (tid == 0) lcand[r * LCR + nl] = make_int2(i, p.w); nl++; }
          }
          break;
        }
        if ((double)p.corr > 0.3 && (p.peak == 0.0f || (double)p.peak > 0.01 * (double)gp)) {
          if (nl < LCR) { if (tid == 0) lcand[r * LCR + nl] = make_int2(i, p.w); nl++; }
        }
      }
      if (tid == 0) lcnt[r] = nl;
    } else {
      int nr = 0, guard = 0;
      for (;;) {
        if (++guard > 500000) break;
        int wcur;
        if (useW && i >= wb0 && i < wb1) wcur = (int)swtab[i - wb0];
        else {
          double fi = useL ? (double)interp1(spitch, S, rr, i) : (double)interp1(pitch, S, rr, i);
          if (fi < 60.0) fi = 60.0;
          int ww = (int)(SRATE / fi); if (ww < 1) ww = 1; if (ww > WMAX - 1) ww = WMAX - 1;
          wcur = ww;
        }
        FPRes p = find_peak_block(snd, lsnd, wb0, wb1, useW, T, i, wcur, true, tid,
                                  refp, sdd, swf, swi, swp);
        i = p.i;
        if (p.corr == -1.0f) i += p.w;
        if (i >= right) {
          if ((double)p.corr > 0.7 && (double)p.peak > 0.023333 * (double)gp) {
            if (nr < RCR) { if (tid == 0) rpk[r * RCR + nr] = i; nr++; }
          }
          break;
        }
        if ((double)p.corr > 0.3 && (p.peak == 0.0f || (double)p.peak > 0.01 * (double)gp)) {
          if (nr < RCR) { if (tid == 0) rpk[r * RCR + nr] = i; nr++; }
        }
      }
      if (tid == 0) rcnt[r] = nr;
    }
  }
}

// ---- merge: wave-parallel filter-count + copy (value-exact via ballot
// prefix), sorted-check + bitonic fallback + clip. ----
__global__ __launch_bounds__(NTM) void kmerge(int T, unsigned* scal,
                                              const int2* __restrict__ lcand, const int* __restrict__ lcnt,
                                              const int* __restrict__ rpk, const int* __restrict__ rcnt,
                                              int* __restrict__ peaks) {
  __shared__ long long arR[RCAP];
  __shared__ long long lastR[RCAP];
  __shared__ int rcs[RCAP];
  __shared__ int lcs[RCAP];
  __shared__ int klc[RCAP];
  __shared__ int off[RCAP + 1];
  __shared__ int sbuf[SCAP];
  __shared__ int unsorted;
  int tid = threadIdx.x;
  int lane = tid & 63, wv = tid >> 6;  // 16 waves
  int nreg = (int)scal[12];
  if (scal[3] == 0u || nreg == 0) { if (tid == 0) scal[4] = 0u; return; }
  if (tid < nreg) {
    int rc = rcnt[tid];
    rcs[tid] = rc;
    lcs[tid] = lcnt[tid];
    lastR[tid] = (rc > 0) ? (long long)rpk[tid * RCR + rc - 1] : LLONG_MIN;
  }
  __syncthreads();
  if (tid == 0) {
    long long ar = -(1LL << 62);
    for (int r = 0; r < nreg; r++) { arR[r] = ar; if (rcs[r] > 0) ar = lastR[r]; }
  }
  __syncthreads();
  for (int r = wv; r < nreg; r += 16) {
    int n = lcs[r];
    long long ar = arR[r];
    int cnt = 0;
    for (int base = 0; base < n; base += 64) {
      int jp = base + lane;
      bool pred = false;
      if (jp < n) {
        int j = n - 1 - jp;
        int2 cd = lcand[r * LCR + j];
        pred = ((double)((long long)cd.x - ar) > 0.8 * (double)cd.y);
      }
      unsigned long long m = __ballot(pred);
      cnt += __popcll(m);
    }
    if (lane == 0) klc[r] = cnt;
  }
  __syncthreads();
  if (tid == 0) {
    int acc = 0;
    for (int r = 0; r < nreg; r++) { off[r] = acc; acc += klc[r] + rcs[r]; if (acc > SCAP) acc = SCAP; }
    off[nreg] = acc;
    scal[4] = (unsigned)acc;
    unsorted = 0;
  }
  __syncthreads();
  for (int r = wv; r < nreg; r += 16) {
    long long ar = arR[r];
    int n = lcs[r];
    int pos0 = off[r];
    for (int base = 0; base < n; base += 64) {
      int jp = base + lane;
      bool pred = false; int val = 0;
      if (jp < n) {
        int j = n - 1 - jp;
        int2 cd = lcand[r * LCR + j];
        if ((double)((long long)cd.x - ar) > 0.8 * (double)cd.y) { pred = true; val = cd.x; }
      }
      unsigned long long m = __ballot(pred);
      if (pred) {
        int pre = __popcll(m & ((1ull << lane) - 1ull));
        int pos = pos0 + pre;
        if (pos < SCAP) peaks[pos] = val;
      }
      pos0 += __popcll(m);
    }
    int rc = rcs[r];
    for (int j = lane; j < rc; j += 64) {
      int pos = pos0 + j;
      if (pos < SCAP) peaks[pos] = rpk[r * RCR + j];
    }
  }
  __syncthreads();
  int npk = off[nreg];
  if (npk > 1) {
    for (int k = tid; k < npk - 1; k += NTM) {
      if (peaks[k] > peaks[k + 1]) unsorted = 1;
    }
    __syncthreads();
    if (unsorted) {
      int n2 = 1; while (n2 < npk) n2 <<= 1;
      for (int k = tid; k < n2; k += NTM) sbuf[k] = (k < npk) ? peaks[k] : INT_MAX;
      __syncthreads();
      for (int kk = 2; kk <= n2; kk <<= 1) {
        for (int j = kk >> 1; j > 0; j >>= 1) {
          for (int idx = tid; idx < n2; idx += NTM) {
            int ixj = idx ^ j;
            if (ixj > idx) {
              int a = sbuf[idx], b = sbuf[ixj];
              bool up = ((idx & kk) == 0);
              if ((up && a > b) || (!up && a < b)) { sbuf[idx] = b; sbuf[ixj] = a; }
            }
          }
          __syncthreads();
        }
      }
      for (int k = tid; k < npk; k += NTM) peaks[k] = sbuf[k];
      __syncthreads();
    }
  }
  for (int k = tid; k < npk; k += NTM) { int v = peaks[k]; if (v < 0) v = 0; if (v > T - 1) v = T - 1; peaks[k] = v; }
}

// ---- psola plan: one BLOCK (256 thr) per region; register-windowed peak
// pointer; vectorized staging (r10, proven). ----
__global__ __launch_bounds__(256) void kplan(const int* __restrict__ pd, int T, unsigned* scal,
                                             const int* __restrict__ peaks,
                                             const int* __restrict__ r1L, const int* __restrict__ r1R,
                                             int4* __restrict__ ops, int* __restrict__ opcnt) {
  __shared__ int sp[PCAP];
  __shared__ int ib[FCAP];
  int tid = threadIdx.x;
  int npk = (int)scal[4];
  int nreg = (int)scal[13];
  int r = (int)blockIdx.x;
  if (scal[3] == 0u || npk == 0) {
    if (r == 0 && tid == 0) { scal[6] = 0u; scal[14] = 0u; }
    return;
  }
  if (r == 0 && tid == 0) {
    scal[6] = (nreg > 0) ? (unsigned)r1R[nreg - 1] : 0u;
    scal[14] = (unsigned)nreg;
  }
  if (r >= nreg) return;
  int prev_right = (r == 0) ? 0 : r1R[r - 1];
  int left_v = r1L[r], right_v = r1R[r];
  int pl_n = npk < PCAP ? npk : PCAP;
  int pl4 = pl_n & ~3;
  for (int k = tid * 4; k < pl4; k += 1024) {
    int4 v = *reinterpret_cast<const int4*>(peaks + k);
    sp[k] = v.x; sp[k + 1] = v.y; sp[k + 2] = v.z; sp[k + 3] = v.w;
  }
  for (int k = pl4 + tid; k < pl_n; k += 256) sp[k] = peaks[k];
  int span = right_v - left_v;
  int fl_n = span < FCAP ? span : FCAP;
  const int* srcp = pd + left_v;
  int head = (4 - (left_v & 3)) & 3; if (head > fl_n) head = fl_n;
  for (int k = tid; k < head; k += 256) ib[k] = srcp[k];
  int rem4 = (fl_n - head) & ~3;
  for (int k = tid * 4; k < rem4; k += 1024) {
    int4 v = *reinterpret_cast<const int4*>(srcp + head + k);
    ib[head + k] = v.x; ib[head + k + 1] = v.y; ib[head + k + 2] = v.z; ib[head + k + 3] = v.w;
  }
  for (int k = head + rem4 + tid; k < fl_n; k += 256) ib[k] = srcp[k];
  __syncthreads();
  if (tid != 0) return;

  auto PRD = [&](int idx) -> int { return (idx < pl_n) ? sp[idx] : peaks[idx]; };

  double minpos = (double)__uint_as_float(scal[1]);
  double max_w = 1.25 * SRATE / minpos;
  int c = 0;
  if (prev_right < left_v) {
    ops[r * OPR + c] = make_int4(prev_right, prev_right, left_v - prev_right, left_v - prev_right);
    c++;
  }
  int lv = left_v, guard = 0;
  int lo = -1;
  int Pm2 = 0, Pm1 = 0, P0 = 0, P1 = 0;
  while (lv < right_v) {
    if (++guard > 500000) break;
    int fo = lv - left_v;
    int period = (fo < fl_n) ? ib[fo] : pd[lv];
    int x = lv;
    if (lo < 0) {
      int a = 0, b = npk;
      while (a < b) { int m = (a + b) >> 1; if (PRD(m) < x) a = m + 1; else b = m; }
      lo = a;
      Pm2 = (lo - 2 >= 0) ? PRD(lo - 2) : 0;
      Pm1 = (lo - 1 >= 0) ? PRD(lo - 1) : 0;
      P0  = (lo < npk) ? PRD(lo) : 0;
      P1  = (lo + 1 < npk) ? PRD(lo + 1) : 0;
    } else {
      while (lo < npk && P0 < x) {
        lo++;
        Pm2 = Pm1; Pm1 = P0; P0 = P1;
        P1 = (lo + 1 < npk) ? PRD(lo + 1) : 0;
      }
    }
    long long d0 = (lo > 0) ? (long long)x - (long long)Pm1 : LLONG_MAX;
    long long d1 = (lo < npk) ? (long long)P0 - (long long)x : LLONG_MAX;
    int p, Pp, Ppm1, Pp1;
    if (d0 <= d1) {
      p = lo - 1;
      int tv = Pm1;
      if (p > 0 && Pm2 == tv) {
        while (p > 0 && PRD(p - 1) == tv) p--;
        Pp = tv;
        Ppm1 = (p > 0) ? PRD(p - 1) : 0;
        Pp1 = (p < npk - 1) ? PRD(p + 1) : 0;
      } else {
        Pp = Pm1; Ppm1 = Pm2; Pp1 = P0;
      }
    } else {
      p = lo; Pp = P0; Ppm1 = Pm1; Pp1 = P1;
    }
    int lw = period >> 1, rw = period >> 1;
    if (p > 0) { long long gp_ = (long long)Pp - (long long)Ppm1; if ((double)gp_ <= max_w && gp_ < (long long)lw) lw = (int)gp_; }
    if (p < npk - 1) { long long gp_ = (long long)Pp1 - (long long)Pp; if ((double)gp_ <= max_w && gp_ < (long long)rw) rw = (int)gp_; }
    int left_i = Pp - lw; if (left_i < 0) left_i = 0;
    int right_i = Pp + rw;
    int ival = (right_i - left_i) >> 1;
    if (ival <= 0) break;
    int a0 = lv - ival;
    int len1 = 0;
    if (a0 >= 0) { int e = lv + ival; if (e > T) e = T; len1 = e - a0; if (len1 < 0) len1 = 0; }
    int e2 = left_i + 2 * ival; if (e2 > T) e2 = T;
    int len2 = e2 - left_i; if (len2 < 0) len2 = 0;
    int seglen = len1 < len2 ? len1 : len2;
    int len_dst = (a0 < 0) ? 0 : ((T - a0 < seglen) ? T - a0 : seglen);
    int len_src = (T - left_i < seglen) ? T - left_i : seglen;
    int L = seglen; if (len_dst < L) L = len_dst; if (len_src < L) L = len_src;
    if (L > 0 && c < OPR) { ops[r * OPR + c] = make_int4(a0, left_i, L, 2 * ival); c++; }
    lv += 2 * ival;
  }
  opcnt[r] = c;
}

// ---- fused output: overlap-add scatter (guarded to dst < tail; adds at
// dst >= tail were overwritten by the tail copy in the reference, so dropping
// them is value-exact) + tail copy, write-disjoint -> safe in one kernel. ----
__global__ __launch_bounds__(256) void kout(const float* __restrict__ snd, float* __restrict__ out,
                                            const unsigned* scal, const int4* __restrict__ ops,
                                            const int* __restrict__ opcnt, int T) {
  int tail = (int)scal[6];
  if (blockIdx.x < APPLYB) {
    int nreg = (int)scal[14];
    int total = nreg * OPR;
    for (int slot = blockIdx.x; slot < total; slot += APPLYB) {
      int r = slot / OPR, j = slot - r * OPR;
      if (j >= opcnt[r]) continue;
      int4 o = ops[r * OPR + j];
      double nn = (double)o.w;
      int kend = o.z;
      { int lim = tail - o.x; if (lim < 0) lim = 0; if (kend > lim) kend = lim; }
      for (int k = threadIdx.x; k < kend; k += blockDim.x) {
        double cph = (6.283185307179586 * (double)k) / nn;
        float wv = (float)(0.5 - 0.5 * cos(cph));
        atomicAdd(out + o.x + k, __fmul_rn(wv, snd[o.y + k]));
      }
    }
  } else {
    int b = blockIdx.x - APPLYB;
    int stride = TAILB * 256;
    for (int t = b * 256 + threadIdx.x; t < T; t += stride)
      if (t >= tail) out[t] = snd[t];
  }
}

extern "C" void kernel_launch(void* const* d_in, const int* in_sizes, int n_in,
                              void* d_out, int out_size, void* d_ws, size_t ws_size,
                              hipStream_t stream) {
  (void)n_in; (void)ws_size;
  int T = in_sizes[0];
  int S = in_sizes[1];
  const float* snd = (const float*)d_in[0];
  const float* pitch = (const float*)d_in[1];
  const int* steps = (const int*)d_in[2];
  const float* prange = (const float*)d_in[3];
  float* out = (float*)d_out;

  char* base = (char*)d_ws;
  size_t off = 0;
  auto alloc = [&](size_t bytes, size_t align) -> char* {
    off = (off + align - 1) & ~(align - 1);
    char* p = base + off;
    off += bytes;
    return p;
  };
  int* pd    = (int*)alloc((size_t)T * 4, 16);
  int* w0    = (int*)alloc((size_t)T * 4, 16);
  unsigned* scal = (unsigned*)alloc(256, 16);
  int* s0l = (int*)alloc(RCAP * 4, 4);
  int* e0l = (int*)alloc(RCAP * 4, 4);
  int* s1l = (int*)alloc(RCAP * 4, 4);
  int* e1l = (int*)alloc(RCAP * 4, 4);
  int* r0L = (int*)alloc(RCAP * 4, 4);
  int* r0R = (int*)alloc(RCAP * 4, 4);
  int* r1L = (int*)alloc(RCAP * 4, 4);
  int* r1R = (int*)alloc(RCAP * 4, 4);
  int* lcnt = (int*)alloc(RCAP * 4, 4);
  int* rcnt = (int*)alloc(RCAP * 4, 4);
  int* opcnt = (int*)alloc(RCAP * 4, 4);
  int2* lcand = (int2*)alloc((size_t)RCAP * LCR * 8, 8);
  int* rpk = (int*)alloc((size_t)RCAP * RCR * 4, 4);
  int* peaks = (int*)alloc((size_t)SCAP * 4, 16);
  int4* ops = (int4*)alloc((size_t)RCAP * OPR * 16, 16);

  hipMemsetAsync(d_out, 0, (size_t)out_size * sizeof(float), stream);
  kstats<<<1, 256, 0, stream>>>(pitch, S, scal);
  kprep<<<1024, 256, 0, stream>>>(pitch, S, T, snd, scal, steps, prange, pd, w0, s0l, e0l, s1l, e1l);
  kregsort2<<<1, 128, 0, stream>>>(T, scal, s0l, e0l, s1l, e1l, r0L, r0R, r1L, r1R);
  kwalk<<<256, NTW, 0, stream>>>(snd, pitch, S, w0, T, scal, r0L, r0R, lcand, lcnt, rpk, rcnt);
  kmerge<<<1, NTM, 0, stream>>>(T, scal, lcand, lcnt, rpk, rcnt, peaks);
  kplan<<<RCAP, 256, 0, stream>>>(pd, T, scal, peaks, r1L, r1R, ops, opcnt);
  kout<<<APPLYB + TAILB, 256, 0, stream>>>(snd, out, scal, ops, opcnt, T);
}